// Round 1
// baseline (753.360 us; speedup 1.0000x reference)
//
#include <hip/hip_runtime.h>
#include <hip/hip_bf16.h>
#include <cmath>

#define H_DIM 3584
#define NH 28
#define NKV 4
#define HD 128
#define S_LEN 2048
#define KQ 3584
#define BK 64
#define LDSK 72   // padded k-stride (elems); 144B rows -> 16B aligned, 2-way banks

typedef __attribute__((ext_vector_type(8))) short bf16x8;
typedef __attribute__((ext_vector_type(4))) float f32x4;

__device__ __forceinline__ unsigned short f2bf(float f) {
  unsigned int u = __builtin_bit_cast(unsigned int, f);
  u += 0x7fffu + ((u >> 16) & 1u);
  return (unsigned short)(u >> 16);
}
__device__ __forceinline__ float bf2f(unsigned short h) {
  unsigned int u = ((unsigned int)h) << 16;
  return __builtin_bit_cast(float, u);
}

// ---------------- elementwise: fp32 -> bf16 ----------------
__global__ void cvt_f32_bf16(const float* __restrict__ in,
                             unsigned short* __restrict__ out, int n4) {
  int i = blockIdx.x * blockDim.x + threadIdx.x;
  if (i >= n4) return;
  float4 f = ((const float4*)in)[i];
  ushort4 v = make_ushort4(f2bf(f.x), f2bf(f.y), f2bf(f.z), f2bf(f.w));
  ((ushort4*)out)[i] = v;
}

// ---------------- RoPE on Q and K (in-place, bf16) ----------------
__global__ void rope_kernel(unsigned short* __restrict__ Q,
                            unsigned short* __restrict__ Kr,
                            const int* __restrict__ pos_ids) {
  int gid = blockIdx.x * blockDim.x + threadIdx.x; // 2048 * 2048
  int s = gid >> 11;
  int p = gid & 2047;
  float pos = (float)pos_ids[s];
  unsigned short* ptr;
  int i;
  if (p < 1792) {           // Q: 28 heads * 64 pairs
    int head = p >> 6; i = p & 63;
    ptr = Q + (size_t)s * H_DIM + head * HD + i;
  } else {                  // K: 4 heads * 64 pairs
    int pk = p - 1792; int head = pk >> 6; i = pk & 63;
    ptr = Kr + (size_t)s * (NKV * HD) + head * HD + i;
  }
  float invf = exp2f(-(float)i * (19.931568569324174f / 64.0f)); // theta^(-i/64)
  float fr = pos * invf;
  float sn, cs;
  sincosf(fr, &sn, &cs);
  float x0 = bf2f(ptr[0]), x1 = bf2f(ptr[64]);
  ptr[0]  = f2bf(x0 * cs - x1 * sn);
  ptr[64] = f2bf(x1 * cs + x0 * sn);
}

// ---------------- GEMM core: C[128x128] = A[128xK] * B[128xK]^T ----------------
// A bf16 row-major, B fp32 row-major (rows = output cols), K = 3584
__device__ __forceinline__ void gemm_core(const unsigned short* __restrict__ A,
                                          const float* __restrict__ Brows,
                                          int bm0, f32x4 (&acc)[4][4],
                                          unsigned short* As, unsigned short* Bs) {
  const int tid = threadIdx.x;
  const int lane = tid & 63;
  const int w = tid >> 6;
  const int wr = w >> 1, wc = w & 1;
  const int lr = lane & 15, lg = lane >> 4;
  const f32x4 zero4 = {0.f, 0.f, 0.f, 0.f};
#pragma unroll
  for (int m = 0; m < 4; ++m)
#pragma unroll
    for (int n = 0; n < 4; ++n) acc[m][n] = zero4;

  for (int k0 = 0; k0 < KQ; k0 += BK) {
#pragma unroll
    for (int it = 0; it < 4; ++it) {  // stage A: 128x64 bf16
      int idx = tid + it * 256;
      int row = idx >> 3;
      int kc = (idx & 7) * 8;
      *(bf16x8*)&As[row * LDSK + kc] =
          *(const bf16x8*)&A[(size_t)(bm0 + row) * KQ + k0 + kc];
    }
#pragma unroll
    for (int it = 0; it < 4; ++it) {  // stage B: 128x64 fp32 -> bf16
      int idx = tid + it * 256;
      int row = idx >> 3;
      int kc = (idx & 7) * 8;
      const float* src = Brows + (size_t)row * KQ + k0 + kc;
      float4 f0 = *(const float4*)src;
      float4 f1 = *(const float4*)(src + 4);
      bf16x8 b;
      b[0] = (short)f2bf(f0.x); b[1] = (short)f2bf(f0.y);
      b[2] = (short)f2bf(f0.z); b[3] = (short)f2bf(f0.w);
      b[4] = (short)f2bf(f1.x); b[5] = (short)f2bf(f1.y);
      b[6] = (short)f2bf(f1.z); b[7] = (short)f2bf(f1.w);
      *(bf16x8*)&Bs[row * LDSK + kc] = b;
    }
    __syncthreads();
#pragma unroll
    for (int kh = 0; kh < 2; ++kh) {
      bf16x8 af[4], bfr[4];
#pragma unroll
      for (int m = 0; m < 4; ++m)
        af[m] = *(const bf16x8*)&As[(wr * 64 + m * 16 + lr) * LDSK + kh * 32 + lg * 8];
#pragma unroll
      for (int n = 0; n < 4; ++n)
        bfr[n] = *(const bf16x8*)&Bs[(wc * 64 + n * 16 + lr) * LDSK + kh * 32 + lg * 8];
#pragma unroll
      for (int m = 0; m < 4; ++m)
#pragma unroll
        for (int n = 0; n < 4; ++n)
          acc[m][n] = __builtin_amdgcn_mfma_f32_16x16x32_bf16(af[m], bfr[n], acc[m][n], 0, 0, 0);
    }
    __syncthreads();
  }
}

// ---------------- fused QKV projection ----------------
__global__ __launch_bounds__(256) void gemm_qkv(
    const unsigned short* __restrict__ Xb,
    const float* __restrict__ wq, const float* __restrict__ bq,
    const float* __restrict__ wk, const float* __restrict__ bk,
    const float* __restrict__ wv, const float* __restrict__ bv,
    unsigned short* __restrict__ Qraw, unsigned short* __restrict__ Kraw,
    unsigned short* __restrict__ Vt) {
  __shared__ unsigned short As[128 * LDSK];
  __shared__ unsigned short Bs[128 * LDSK];
  const int bm0 = blockIdx.x * 128;
  const int cb = blockIdx.y;  // 0..35 : 28 Q blocks, 4 K blocks, 4 V blocks
  const float* Brows; const float* bias; int seg, c0;
  if (cb < 28)      { seg = 0; c0 = cb * 128;        Brows = wq + (size_t)c0 * KQ; bias = bq + c0; }
  else if (cb < 32) { seg = 1; c0 = (cb - 28) * 128; Brows = wk + (size_t)c0 * KQ; bias = bk + c0; }
  else              { seg = 2; c0 = (cb - 32) * 128; Brows = wv + (size_t)c0 * KQ; bias = bv + c0; }
  f32x4 acc[4][4];
  gemm_core(Xb, Brows, bm0, acc, As, Bs);
  const int tid = threadIdx.x, lane = tid & 63, w = tid >> 6;
  const int wr = w >> 1, wc = w & 1, lr = lane & 15, lg = lane >> 4;
#pragma unroll
  for (int m = 0; m < 4; ++m) {
#pragma unroll
    for (int n = 0; n < 4; ++n) {
      int coll = wc * 64 + n * 16 + lr;
      float bb = bias[coll];
#pragma unroll
      for (int r = 0; r < 4; ++r) {
        int row = bm0 + wr * 64 + m * 16 + lg * 4 + r;
        float v = acc[m][n][r] + bb;
        if (seg == 0)      Qraw[(size_t)row * H_DIM + c0 + coll] = f2bf(v);
        else if (seg == 1) Kraw[(size_t)row * (NKV * HD) + c0 + coll] = f2bf(v);
        else               Vt[(size_t)(c0 + coll) * S_LEN + row] = f2bf(v);  // transposed
      }
    }
  }
}

// ---------------- output projection ----------------
__global__ __launch_bounds__(256) void gemm_out(
    const unsigned short* __restrict__ Ctx,
    const float* __restrict__ wo,
    float* __restrict__ out) {
  __shared__ unsigned short As[128 * LDSK];
  __shared__ unsigned short Bs[128 * LDSK];
  const int bm0 = blockIdx.x * 128;
  const int c0 = blockIdx.y * 128;
  f32x4 acc[4][4];
  gemm_core(Ctx, wo + (size_t)c0 * KQ, bm0, acc, As, Bs);
  const int tid = threadIdx.x, lane = tid & 63, w = tid >> 6;
  const int wr = w >> 1, wc = w & 1, lr = lane & 15, lg = lane >> 4;
#pragma unroll
  for (int m = 0; m < 4; ++m)
#pragma unroll
    for (int n = 0; n < 4; ++n) {
      int coll = wc * 64 + n * 16 + lr;
#pragma unroll
      for (int r = 0; r < 4; ++r) {
        int row = bm0 + wr * 64 + m * 16 + lg * 4 + r;
        out[(size_t)row * H_DIM + c0 + coll] = acc[m][n][r];
      }
    }
}

// ---------------- flash attention (causal, GQA 7:1) ----------------
__global__ __launch_bounds__(256) void attn_kernel(
    const unsigned short* __restrict__ Q,
    const unsigned short* __restrict__ K,
    const unsigned short* __restrict__ Vt,
    unsigned short* __restrict__ Ctx) {
  __shared__ unsigned short plds[4][16][48];  // per-wave P transpose buffer
  const int h = blockIdx.x;       // 0..27
  const int qt = blockIdx.y;      // 0..31, 64 q-rows each
  const int hkv = h / 7;
  const int tid = threadIdx.x, w = tid >> 6, lane = tid & 63;
  const int lr = lane & 15, lg = lane >> 4;
  const int q0 = qt * 64 + w * 16;
  const float scale = 0.08838834764831845f;   // 1/sqrt(128)
  const float l2e = 1.4426950408889634f;

  bf16x8 aq[4];
  const unsigned short* qrow = Q + (size_t)(q0 + lr) * H_DIM + h * HD;
#pragma unroll
  for (int ds = 0; ds < 4; ++ds) aq[ds] = *(const bf16x8*)(qrow + ds * 32 + lg * 8);

  const f32x4 zero4 = {0.f, 0.f, 0.f, 0.f};
  f32x4 acc[8];
#pragma unroll
  for (int t = 0; t < 8; ++t) acc[t] = zero4;
  float mrun[4] = {-1e30f, -1e30f, -1e30f, -1e30f};
  float lrun[4] = {0.f, 0.f, 0.f, 0.f};

  const int nkt = (q0 + 47) >> 5;  // wave-local causal tile count (32 keys/tile)
  for (int kt = 0; kt < nkt; ++kt) {
    const int k0 = kt * 32;
    f32x4 s[2];
    s[0] = zero4; s[1] = zero4;
#pragma unroll
    for (int kk = 0; kk < 2; ++kk) {
      const unsigned short* krow = K + (size_t)(k0 + kk * 16 + lr) * (NKV * HD) + hkv * HD;
#pragma unroll
      for (int ds = 0; ds < 4; ++ds) {
        bf16x8 bk = *(const bf16x8*)(krow + ds * 32 + lg * 8);
        s[kk] = __builtin_amdgcn_mfma_f32_16x16x32_bf16(aq[ds], bk, s[kk], 0, 0, 0);
      }
    }
    float sv[2][4];
#pragma unroll
    for (int kk = 0; kk < 2; ++kk) {
      int key = k0 + kk * 16 + lr;
#pragma unroll
      for (int r = 0; r < 4; ++r) {
        int qr = q0 + lg * 4 + r;
        float v = s[kk][r] * scale;
        sv[kk][r] = (key > qr) ? -1e30f : v;
      }
    }
    float mt[4];
#pragma unroll
    for (int r = 0; r < 4; ++r) mt[r] = fmaxf(sv[0][r], sv[1][r]);
#pragma unroll
    for (int sh = 0; sh < 4; ++sh) {
      int off = 1 << sh;
#pragma unroll
      for (int r = 0; r < 4; ++r) mt[r] = fmaxf(mt[r], __shfl_xor(mt[r], off));
    }
    float mnew[4], alpha[4];
#pragma unroll
    for (int r = 0; r < 4; ++r) {
      mnew[r] = fmaxf(mrun[r], mt[r]);
      alpha[r] = exp2f((mrun[r] - mnew[r]) * l2e);
      mrun[r] = mnew[r];
    }
    float p[2][4], lt[4];
#pragma unroll
    for (int r = 0; r < 4; ++r) lt[r] = 0.f;
#pragma unroll
    for (int kk = 0; kk < 2; ++kk)
#pragma unroll
      for (int r = 0; r < 4; ++r) {
        p[kk][r] = exp2f((sv[kk][r] - mnew[r]) * l2e);
        lt[r] += p[kk][r];
      }
#pragma unroll
    for (int sh = 0; sh < 4; ++sh) {
      int off = 1 << sh;
#pragma unroll
      for (int r = 0; r < 4; ++r) lt[r] += __shfl_xor(lt[r], off);
    }
#pragma unroll
    for (int r = 0; r < 4; ++r) lrun[r] = lrun[r] * alpha[r] + lt[r];
#pragma unroll
    for (int t = 0; t < 8; ++t)
#pragma unroll
      for (int r = 0; r < 4; ++r) acc[t][r] *= alpha[r];
    // P -> bf16, transpose via per-wave LDS (wave-coherent, no block barrier)
#pragma unroll
    for (int kk = 0; kk < 2; ++kk)
#pragma unroll
      for (int r = 0; r < 4; ++r)
        plds[w][lg * 4 + r][kk * 16 + lr] = f2bf(p[kk][r]);
    bf16x8 pa = *(const bf16x8*)&plds[w][lr][lg * 8];
    const unsigned short* vbase = Vt + (size_t)(hkv * HD) * S_LEN + k0 + lg * 8;
#pragma unroll
    for (int t = 0; t < 8; ++t) {
      bf16x8 bv8 = *(const bf16x8*)(vbase + (size_t)(t * 16 + lr) * S_LEN);
      acc[t] = __builtin_amdgcn_mfma_f32_16x16x32_bf16(pa, bv8, acc[t], 0, 0, 0);
    }
  }
#pragma unroll
  for (int r = 0; r < 4; ++r) {
    float inv = 1.0f / lrun[r];
#pragma unroll
    for (int t = 0; t < 8; ++t)
      Ctx[(size_t)(q0 + lg * 4 + r) * H_DIM + h * HD + t * 16 + lr] = f2bf(acc[t][r] * inv);
  }
}

extern "C" void kernel_launch(void* const* d_in, const int* in_sizes, int n_in,
                              void* d_out, int out_size, void* d_ws, size_t ws_size,
                              hipStream_t stream) {
  (void)in_sizes; (void)n_in; (void)out_size; (void)ws_size;
  const float* hidden = (const float*)d_in[0];
  const float* wq = (const float*)d_in[1];
  const float* bq = (const float*)d_in[2];
  const float* wk = (const float*)d_in[3];
  const float* bk = (const float*)d_in[4];
  const float* wv = (const float*)d_in[5];
  const float* bv = (const float*)d_in[6];
  const float* wo = (const float*)d_in[7];
  const int* pos = (const int*)d_in[8];
  float* out = (float*)d_out;

  // workspace layout (bf16 elems): Xb | Qraw | Kraw | Vt | Ctx  (~48.2 MB)
  unsigned short* Xb   = (unsigned short*)d_ws;
  unsigned short* Qraw = Xb   + (size_t)S_LEN * H_DIM;
  unsigned short* Kraw = Qraw + (size_t)S_LEN * H_DIM;
  unsigned short* Vt   = Kraw + (size_t)S_LEN * (NKV * HD);
  unsigned short* Ctx  = Vt   + (size_t)S_LEN * (NKV * HD);

  cvt_f32_bf16<<<(S_LEN * H_DIM / 4 + 255) / 256, 256, 0, stream>>>(hidden, Xb, S_LEN * H_DIM / 4);
  gemm_qkv<<<dim3(16, 36), 256, 0, stream>>>(Xb, wq, bq, wk, bk, wv, bv, Qraw, Kraw, Vt);
  rope_kernel<<<(S_LEN * 2048) / 256, 256, 0, stream>>>(Qraw, Kraw, pos);
  attn_kernel<<<dim3(NH, S_LEN / 64), 256, 0, stream>>>(Qraw, Kraw, Vt, Ctx);
  gemm_out<<<dim3(16, 28), 256, 0, stream>>>(Ctx, wo, out);
}

// Round 2
// 674.889 us; speedup vs baseline: 1.1163x; 1.1163x over previous
//
#include <hip/hip_runtime.h>
#include <hip/hip_bf16.h>
#include <cmath>

#define H_DIM 3584
#define NH 28
#define NKV 4
#define HD 128
#define S_LEN 2048
#define KQ 3584
#define KV_DIM 512
#define LDSK 72   // padded k-stride for fallback gemm

typedef __attribute__((ext_vector_type(8))) short bf16x8;
typedef __attribute__((ext_vector_type(4))) float f32x4;

__device__ __forceinline__ unsigned short f2bf(float f) {
  unsigned int u = __builtin_bit_cast(unsigned int, f);
  u += 0x7fffu + ((u >> 16) & 1u);
  return (unsigned short)(u >> 16);
}
__device__ __forceinline__ float bf2f(unsigned short h) {
  unsigned int u = ((unsigned int)h) << 16;
  return __builtin_bit_cast(float, u);
}

// ---------------- elementwise: fp32 -> bf16 ----------------
__global__ void cvt_f32_bf16(const float* __restrict__ in,
                             unsigned short* __restrict__ out, int n4) {
  int i = blockIdx.x * blockDim.x + threadIdx.x;
  if (i >= n4) return;
  float4 f = ((const float4*)in)[i];
  ushort4 v = make_ushort4(f2bf(f.x), f2bf(f.y), f2bf(f.z), f2bf(f.w));
  ((ushort4*)out)[i] = v;
}

// ---------------- RoPE on Q and K (in-place, bf16) ----------------
__global__ void rope_kernel(unsigned short* __restrict__ Q,
                            unsigned short* __restrict__ Kr,
                            const int* __restrict__ pos_ids) {
  int gid = blockIdx.x * blockDim.x + threadIdx.x; // 2048 * 2048
  int s = gid >> 11;
  int p = gid & 2047;
  float pos = (float)pos_ids[s];
  unsigned short* ptr;
  int i;
  if (p < 1792) {           // Q: 28 heads * 64 pairs
    int head = p >> 6; i = p & 63;
    ptr = Q + (size_t)s * H_DIM + head * HD + i;
  } else {                  // K: 4 heads * 64 pairs
    int pk = p - 1792; int head = pk >> 6; i = pk & 63;
    ptr = Kr + (size_t)s * KV_DIM + head * HD + i;
  }
  float invf = exp2f(-(float)i * (19.931568569324174f / 64.0f)); // theta^(-i/64)
  float fr = pos * invf;
  float sn, cs;
  sincosf(fr, &sn, &cs);
  float x0 = bf2f(ptr[0]), x1 = bf2f(ptr[64]);
  ptr[0]  = f2bf(x0 * cs - x1 * sn);
  ptr[64] = f2bf(x1 * cs + x0 * sn);
}

// =======================================================================
// FAST GEMM (m97 structure): both operands bf16, global_load_lds width 16,
// 128x128 tile, BK=64, linear LDS (no pad), 2 barriers per K-step.
// =======================================================================
__device__ __forceinline__ void gemm_core_fast(const unsigned short* __restrict__ A,
                                               const unsigned short* __restrict__ B,
                                               int bm0, f32x4 (&acc)[4][4],
                                               unsigned short* As, unsigned short* Bs) {
  const int tid = threadIdx.x, lane = tid & 63, w = tid >> 6;
  const int wr = w >> 1, wc = w & 1, lr = lane & 15, lg = lane >> 4;
  const f32x4 zero4 = {0.f, 0.f, 0.f, 0.f};
#pragma unroll
  for (int m = 0; m < 4; ++m)
#pragma unroll
    for (int n = 0; n < 4; ++n) acc[m][n] = zero4;

  const int lrow = lane >> 3;        // 0..7
  const int lcol = (lane & 7) * 8;   // elem col within 64

  for (int k0 = 0; k0 < KQ; k0 += 64) {
#pragma unroll
    for (int j = 0; j < 4; ++j) {
      int id = w * 4 + j;            // 0..15, wave-uniform
      int row = id * 8 + lrow;       // 0..127
      __builtin_amdgcn_global_load_lds(
          (const __attribute__((address_space(1))) unsigned int*)(A + (size_t)(bm0 + row) * KQ + k0 + lcol),
          (__attribute__((address_space(3))) unsigned int*)(As + id * 512),
          16, 0, 0);
      __builtin_amdgcn_global_load_lds(
          (const __attribute__((address_space(1))) unsigned int*)(B + (size_t)row * KQ + k0 + lcol),
          (__attribute__((address_space(3))) unsigned int*)(Bs + id * 512),
          16, 0, 0);
    }
    __syncthreads();
#pragma unroll
    for (int kh = 0; kh < 2; ++kh) {
      bf16x8 af[4], bfr[4];
#pragma unroll
      for (int m = 0; m < 4; ++m)
        af[m] = *(const bf16x8*)&As[(wr * 64 + m * 16 + lr) * 64 + kh * 32 + lg * 8];
#pragma unroll
      for (int n = 0; n < 4; ++n)
        bfr[n] = *(const bf16x8*)&Bs[(wc * 64 + n * 16 + lr) * 64 + kh * 32 + lg * 8];
#pragma unroll
      for (int m = 0; m < 4; ++m)
#pragma unroll
        for (int n = 0; n < 4; ++n)
          acc[m][n] = __builtin_amdgcn_mfma_f32_16x16x32_bf16(af[m], bfr[n], acc[m][n], 0, 0, 0);
    }
    __syncthreads();
  }
}

__global__ __launch_bounds__(256) void gemm_qkv_fast(
    const unsigned short* __restrict__ Xb,
    const unsigned short* __restrict__ Wqb, const float* __restrict__ bq,
    const unsigned short* __restrict__ Wkb, const float* __restrict__ bk,
    const unsigned short* __restrict__ Wvb, const float* __restrict__ bv,
    unsigned short* __restrict__ Qraw, unsigned short* __restrict__ Kraw,
    unsigned short* __restrict__ Vt) {
  __shared__ unsigned short As[128 * 64];
  __shared__ unsigned short Bs[128 * 64];
  const int bm0 = blockIdx.x * 128;
  const int cb = blockIdx.y;
  const unsigned short* Brows; const float* bias; int seg, c0;
  if (cb < 28)      { seg = 0; c0 = cb * 128;        Brows = Wqb + (size_t)c0 * KQ; bias = bq + c0; }
  else if (cb < 32) { seg = 1; c0 = (cb - 28) * 128; Brows = Wkb + (size_t)c0 * KQ; bias = bk + c0; }
  else              { seg = 2; c0 = (cb - 32) * 128; Brows = Wvb + (size_t)c0 * KQ; bias = bv + c0; }
  f32x4 acc[4][4];
  gemm_core_fast(Xb, Brows, bm0, acc, As, Bs);
  const int tid = threadIdx.x, lane = tid & 63, w = tid >> 6;
  const int wr = w >> 1, wc = w & 1, lr = lane & 15, lg = lane >> 4;
#pragma unroll
  for (int m = 0; m < 4; ++m) {
#pragma unroll
    for (int n = 0; n < 4; ++n) {
      int coll = wc * 64 + n * 16 + lr;
      float bb = bias[coll];
#pragma unroll
      for (int r = 0; r < 4; ++r) {
        int row = bm0 + wr * 64 + m * 16 + lg * 4 + r;
        float v = acc[m][n][r] + bb;
        if (seg == 0)      Qraw[(size_t)row * H_DIM + c0 + coll] = f2bf(v);
        else if (seg == 1) Kraw[(size_t)row * KV_DIM + c0 + coll] = f2bf(v);
        else               Vt[(size_t)(c0 + coll) * S_LEN + row] = f2bf(v);
      }
    }
  }
}

__global__ __launch_bounds__(256) void gemm_out_fast(
    const unsigned short* __restrict__ Ctx,
    const unsigned short* __restrict__ Wob,
    float* __restrict__ out) {
  __shared__ unsigned short As[128 * 64];
  __shared__ unsigned short Bs[128 * 64];
  const int bm0 = blockIdx.x * 128;
  const int c0 = blockIdx.y * 128;
  f32x4 acc[4][4];
  gemm_core_fast(Ctx, Wob + (size_t)c0 * KQ, bm0, acc, As, Bs);
  const int tid = threadIdx.x, lane = tid & 63, w = tid >> 6;
  const int wr = w >> 1, wc = w & 1, lr = lane & 15, lg = lane >> 4;
#pragma unroll
  for (int m = 0; m < 4; ++m)
#pragma unroll
    for (int n = 0; n < 4; ++n) {
      int coll = wc * 64 + n * 16 + lr;
#pragma unroll
      for (int r = 0; r < 4; ++r) {
        int row = bm0 + wr * 64 + m * 16 + lg * 4 + r;
        out[(size_t)row * H_DIM + c0 + coll] = acc[m][n][r];
      }
    }
}

// =======================================================================
// FALLBACK GEMM (inline fp32->bf16 B conversion) — used if ws too small
// =======================================================================
__device__ __forceinline__ void gemm_core_slow(const unsigned short* __restrict__ A,
                                               const float* __restrict__ Brows,
                                               int bm0, f32x4 (&acc)[4][4],
                                               unsigned short* As, unsigned short* Bs) {
  const int tid = threadIdx.x;
  const int lane = tid & 63;
  const int w = tid >> 6;
  const int wr = w >> 1, wc = w & 1;
  const int lr = lane & 15, lg = lane >> 4;
  const f32x4 zero4 = {0.f, 0.f, 0.f, 0.f};
#pragma unroll
  for (int m = 0; m < 4; ++m)
#pragma unroll
    for (int n = 0; n < 4; ++n) acc[m][n] = zero4;

  for (int k0 = 0; k0 < KQ; k0 += 64) {
#pragma unroll
    for (int it = 0; it < 4; ++it) {
      int idx = tid + it * 256;
      int row = idx >> 3;
      int kc = (idx & 7) * 8;
      *(bf16x8*)&As[row * LDSK + kc] =
          *(const bf16x8*)&A[(size_t)(bm0 + row) * KQ + k0 + kc];
    }
#pragma unroll
    for (int it = 0; it < 4; ++it) {
      int idx = tid + it * 256;
      int row = idx >> 3;
      int kc = (idx & 7) * 8;
      const float* src = Brows + (size_t)row * KQ + k0 + kc;
      float4 f0 = *(const float4*)src;
      float4 f1 = *(const float4*)(src + 4);
      bf16x8 b;
      b[0] = (short)f2bf(f0.x); b[1] = (short)f2bf(f0.y);
      b[2] = (short)f2bf(f0.z); b[3] = (short)f2bf(f0.w);
      b[4] = (short)f2bf(f1.x); b[5] = (short)f2bf(f1.y);
      b[6] = (short)f2bf(f1.z); b[7] = (short)f2bf(f1.w);
      *(bf16x8*)&Bs[row * LDSK + kc] = b;
    }
    __syncthreads();
#pragma unroll
    for (int kh = 0; kh < 2; ++kh) {
      bf16x8 af[4], bfr[4];
#pragma unroll
      for (int m = 0; m < 4; ++m)
        af[m] = *(const bf16x8*)&As[(wr * 64 + m * 16 + lr) * LDSK + kh * 32 + lg * 8];
#pragma unroll
      for (int n = 0; n < 4; ++n)
        bfr[n] = *(const bf16x8*)&Bs[(wc * 64 + n * 16 + lr) * LDSK + kh * 32 + lg * 8];
#pragma unroll
      for (int m = 0; m < 4; ++m)
#pragma unroll
        for (int n = 0; n < 4; ++n)
          acc[m][n] = __builtin_amdgcn_mfma_f32_16x16x32_bf16(af[m], bfr[n], acc[m][n], 0, 0, 0);
    }
    __syncthreads();
  }
}

__global__ __launch_bounds__(256) void gemm_qkv_slow(
    const unsigned short* __restrict__ Xb,
    const float* __restrict__ wq, const float* __restrict__ bq,
    const float* __restrict__ wk, const float* __restrict__ bk,
    const float* __restrict__ wv, const float* __restrict__ bv,
    unsigned short* __restrict__ Qraw, unsigned short* __restrict__ Kraw,
    unsigned short* __restrict__ Vt) {
  __shared__ unsigned short As[128 * LDSK];
  __shared__ unsigned short Bs[128 * LDSK];
  const int bm0 = blockIdx.x * 128;
  const int cb = blockIdx.y;
  const float* Brows; const float* bias; int seg, c0;
  if (cb < 28)      { seg = 0; c0 = cb * 128;        Brows = wq + (size_t)c0 * KQ; bias = bq + c0; }
  else if (cb < 32) { seg = 1; c0 = (cb - 28) * 128; Brows = wk + (size_t)c0 * KQ; bias = bk + c0; }
  else              { seg = 2; c0 = (cb - 32) * 128; Brows = wv + (size_t)c0 * KQ; bias = bv + c0; }
  f32x4 acc[4][4];
  gemm_core_slow(Xb, Brows, bm0, acc, As, Bs);
  const int tid = threadIdx.x, lane = tid & 63, w = tid >> 6;
  const int wr = w >> 1, wc = w & 1, lr = lane & 15, lg = lane >> 4;
#pragma unroll
  for (int m = 0; m < 4; ++m) {
#pragma unroll
    for (int n = 0; n < 4; ++n) {
      int coll = wc * 64 + n * 16 + lr;
      float bb = bias[coll];
#pragma unroll
      for (int r = 0; r < 4; ++r) {
        int row = bm0 + wr * 64 + m * 16 + lg * 4 + r;
        float v = acc[m][n][r] + bb;
        if (seg == 0)      Qraw[(size_t)row * H_DIM + c0 + coll] = f2bf(v);
        else if (seg == 1) Kraw[(size_t)row * KV_DIM + c0 + coll] = f2bf(v);
        else               Vt[(size_t)(c0 + coll) * S_LEN + row] = f2bf(v);
      }
    }
  }
}

__global__ __launch_bounds__(256) void gemm_out_slow(
    const unsigned short* __restrict__ Ctx,
    const float* __restrict__ wo,
    float* __restrict__ out) {
  __shared__ unsigned short As[128 * LDSK];
  __shared__ unsigned short Bs[128 * LDSK];
  const int bm0 = blockIdx.x * 128;
  const int c0 = blockIdx.y * 128;
  f32x4 acc[4][4];
  gemm_core_slow(Ctx, wo + (size_t)c0 * KQ, bm0, acc, As, Bs);
  const int tid = threadIdx.x, lane = tid & 63, w = tid >> 6;
  const int wr = w >> 1, wc = w & 1, lr = lane & 15, lg = lane >> 4;
#pragma unroll
  for (int m = 0; m < 4; ++m)
#pragma unroll
    for (int n = 0; n < 4; ++n) {
      int coll = wc * 64 + n * 16 + lr;
#pragma unroll
      for (int r = 0; r < 4; ++r) {
        int row = bm0 + wr * 64 + m * 16 + lg * 4 + r;
        out[(size_t)row * H_DIM + c0 + coll] = acc[m][n][r];
      }
    }
}

// =======================================================================
// Flash attention v2: 1 wave per block, 32 q-rows/wave, 64-key tiles,
// K/V direct from L2, defer-max rescale, reversed-qt load balance.
// =======================================================================
__global__ __launch_bounds__(64) void attn2_kernel(
    const unsigned short* __restrict__ Q,
    const unsigned short* __restrict__ K,
    const unsigned short* __restrict__ Vt,
    unsigned short* __restrict__ Ctx) {
  __shared__ unsigned short plds[2][16][72];
  const int h = blockIdx.y;
  const int qt = (int)gridDim.x - 1 - (int)blockIdx.x;  // heavy blocks first
  const int hkv = h / 7;
  const int lane = threadIdx.x & 63;
  const int lr = lane & 15, lg = lane >> 4;
  const int q0 = qt * 32;
  const float scale = 0.08838834764831845f;   // 1/sqrt(128)
  const float l2e = 1.4426950408889634f;

  bf16x8 aq[2][4];
#pragma unroll
  for (int qf = 0; qf < 2; ++qf) {
    const unsigned short* qrow = Q + (size_t)(q0 + qf * 16 + lr) * H_DIM + h * HD;
#pragma unroll
    for (int ds = 0; ds < 4; ++ds) aq[qf][ds] = *(const bf16x8*)(qrow + ds * 32 + lg * 8);
  }

  const f32x4 zero4 = {0.f, 0.f, 0.f, 0.f};
  f32x4 acc[2][8];
#pragma unroll
  for (int qf = 0; qf < 2; ++qf)
#pragma unroll
    for (int t = 0; t < 8; ++t) acc[qf][t] = zero4;
  float mrun[2][4], lrun[2][4];
#pragma unroll
  for (int qf = 0; qf < 2; ++qf)
#pragma unroll
    for (int r = 0; r < 4; ++r) { mrun[qf][r] = -1e30f; lrun[qf][r] = 0.f; }

  const unsigned short* kbase = K + hkv * HD + (size_t)lr * KV_DIM + lg * 8;
  const unsigned short* vbase = Vt + (size_t)(hkv * HD + lr) * S_LEN + lg * 8;

  const int nkt = (q0 + 95) >> 6;
  for (int kt = 0; kt < nkt; ++kt) {
    const int k0 = kt * 64;
    f32x4 s[2][4];
#pragma unroll
    for (int qf = 0; qf < 2; ++qf)
#pragma unroll
      for (int kf = 0; kf < 4; ++kf) s[qf][kf] = zero4;
#pragma unroll
    for (int kf = 0; kf < 4; ++kf) {
      const unsigned short* kp = kbase + (size_t)(k0 + kf * 16) * KV_DIM;
      bf16x8 kb[4];
#pragma unroll
      for (int ds = 0; ds < 4; ++ds) kb[ds] = *(const bf16x8*)(kp + ds * 32);
#pragma unroll
      for (int ds = 0; ds < 4; ++ds) {
        s[0][kf] = __builtin_amdgcn_mfma_f32_16x16x32_bf16(aq[0][ds], kb[ds], s[0][kf], 0, 0, 0);
        s[1][kf] = __builtin_amdgcn_mfma_f32_16x16x32_bf16(aq[1][ds], kb[ds], s[1][kf], 0, 0, 0);
      }
    }
    // mask + scale
    float sv[2][4][4];
#pragma unroll
    for (int qf = 0; qf < 2; ++qf)
#pragma unroll
      for (int kf = 0; kf < 4; ++kf) {
        int key = k0 + kf * 16 + lr;
#pragma unroll
        for (int r = 0; r < 4; ++r) {
          int qr = q0 + qf * 16 + lg * 4 + r;
          sv[qf][kf][r] = (key > qr) ? -1e30f : s[qf][kf][r] * scale;
        }
      }
    // row max (per (qf,r) over 64 keys: 4 kf in-lane + 16-lane shuffle)
    float mt[2][4];
#pragma unroll
    for (int qf = 0; qf < 2; ++qf)
#pragma unroll
      for (int r = 0; r < 4; ++r)
        mt[qf][r] = fmaxf(fmaxf(sv[qf][0][r], sv[qf][1][r]), fmaxf(sv[qf][2][r], sv[qf][3][r]));
#pragma unroll
    for (int sh = 0; sh < 4; ++sh) {
      int off = 1 << sh;
#pragma unroll
      for (int qf = 0; qf < 2; ++qf)
#pragma unroll
        for (int r = 0; r < 4; ++r) mt[qf][r] = fmaxf(mt[qf][r], __shfl_xor(mt[qf][r], off));
    }
    // defer-max: only rescale when some row's max grew
    bool need = false;
#pragma unroll
    for (int qf = 0; qf < 2; ++qf)
#pragma unroll
      for (int r = 0; r < 4; ++r) need = need || (mt[qf][r] > mrun[qf][r]);
    if (__any(need)) {
#pragma unroll
      for (int qf = 0; qf < 2; ++qf)
#pragma unroll
        for (int r = 0; r < 4; ++r) {
          float mnew = fmaxf(mrun[qf][r], mt[qf][r]);
          float alpha = exp2f((mrun[qf][r] - mnew) * l2e);
          mrun[qf][r] = mnew;
          lrun[qf][r] *= alpha;
#pragma unroll
          for (int t = 0; t < 8; ++t) acc[qf][t][r] *= alpha;
        }
    }
    // p = exp(sv - m), row-sum, write transposed to LDS
    float lt[2][4];
#pragma unroll
    for (int qf = 0; qf < 2; ++qf)
#pragma unroll
      for (int r = 0; r < 4; ++r) lt[qf][r] = 0.f;
#pragma unroll
    for (int qf = 0; qf < 2; ++qf)
#pragma unroll
      for (int kf = 0; kf < 4; ++kf)
#pragma unroll
        for (int r = 0; r < 4; ++r) {
          float p = exp2f((sv[qf][kf][r] - mrun[qf][r]) * l2e);
          lt[qf][r] += p;
          plds[qf][lg * 4 + r][kf * 16 + lr] = f2bf(p);
        }
#pragma unroll
    for (int sh = 0; sh < 4; ++sh) {
      int off = 1 << sh;
#pragma unroll
      for (int qf = 0; qf < 2; ++qf)
#pragma unroll
        for (int r = 0; r < 4; ++r) lt[qf][r] += __shfl_xor(lt[qf][r], off);
    }
#pragma unroll
    for (int qf = 0; qf < 2; ++qf)
#pragma unroll
      for (int r = 0; r < 4; ++r) lrun[qf][r] += lt[qf][r];
    // PV: V frags shared across both q-frags
#pragma unroll
    for (int ks = 0; ks < 2; ++ks) {
      bf16x8 pa0 = *(const bf16x8*)&plds[0][lr][ks * 32 + lg * 8];
      bf16x8 pa1 = *(const bf16x8*)&plds[1][lr][ks * 32 + lg * 8];
#pragma unroll
      for (int t = 0; t < 8; ++t) {
        bf16x8 vb = *(const bf16x8*)(vbase + (size_t)(t * 16) * S_LEN + k0 + ks * 32);
        acc[0][t] = __builtin_amdgcn_mfma_f32_16x16x32_bf16(pa0, vb, acc[0][t], 0, 0, 0);
        acc[1][t] = __builtin_amdgcn_mfma_f32_16x16x32_bf16(pa1, vb, acc[1][t], 0, 0, 0);
      }
    }
  }
#pragma unroll
  for (int qf = 0; qf < 2; ++qf)
#pragma unroll
    for (int r = 0; r < 4; ++r) {
      float inv = 1.0f / lrun[qf][r];
#pragma unroll
      for (int t = 0; t < 8; ++t)
        Ctx[(size_t)(q0 + qf * 16 + lg * 4 + r) * H_DIM + h * HD + t * 16 + lr] =
            f2bf(acc[qf][t][r] * inv);
    }
}

extern "C" void kernel_launch(void* const* d_in, const int* in_sizes, int n_in,
                              void* d_out, int out_size, void* d_ws, size_t ws_size,
                              hipStream_t stream) {
  (void)in_sizes; (void)n_in; (void)out_size;
  const float* hidden = (const float*)d_in[0];
  const float* wq = (const float*)d_in[1];
  const float* bq = (const float*)d_in[2];
  const float* wk = (const float*)d_in[3];
  const float* bk = (const float*)d_in[4];
  const float* wv = (const float*)d_in[5];
  const float* bv = (const float*)d_in[6];
  const float* wo = (const float*)d_in[7];
  const int* pos = (const int*)d_in[8];
  float* out = (float*)d_out;

  const size_t N_X   = (size_t)S_LEN * H_DIM;   // 7,340,032
  const size_t N_KV  = (size_t)S_LEN * KV_DIM;  // 1,048,576
  const size_t N_WQ  = (size_t)NH * HD * H_DIM; // 12,845,056
  const size_t N_WK  = (size_t)NKV * HD * H_DIM;// 1,835,008

  unsigned short* Xb   = (unsigned short*)d_ws;
  unsigned short* Qraw = Xb   + N_X;
  unsigned short* Kraw = Qraw + N_X;
  unsigned short* Vt   = Kraw + N_KV;
  unsigned short* Ctx  = Vt   + N_KV;
  unsigned short* Wqb  = Ctx  + N_X;
  unsigned short* Wkb  = Wqb  + N_WQ;
  unsigned short* Wvb  = Wkb  + N_WK;
  unsigned short* Wob  = Wvb  + N_WK;

  const size_t NEED_FAST = (3 * N_X + 2 * N_KV + 2 * N_WQ + 2 * N_WK) * sizeof(unsigned short);
  const bool fast = ws_size >= NEED_FAST;

  cvt_f32_bf16<<<(int)(N_X / 4 / 256), 256, 0, stream>>>(hidden, Xb, (int)(N_X / 4));

  if (fast) {
    cvt_f32_bf16<<<(int)(N_WQ / 4 / 256), 256, 0, stream>>>(wq, Wqb, (int)(N_WQ / 4));
    cvt_f32_bf16<<<(int)(N_WK / 4 / 256), 256, 0, stream>>>(wk, Wkb, (int)(N_WK / 4));
    cvt_f32_bf16<<<(int)(N_WK / 4 / 256), 256, 0, stream>>>(wv, Wvb, (int)(N_WK / 4));
    cvt_f32_bf16<<<(int)(N_WQ / 4 / 256), 256, 0, stream>>>(wo, Wob, (int)(N_WQ / 4));
    gemm_qkv_fast<<<dim3(16, 36), 256, 0, stream>>>(Xb, Wqb, bq, Wkb, bk, Wvb, bv, Qraw, Kraw, Vt);
  } else {
    gemm_qkv_slow<<<dim3(16, 36), 256, 0, stream>>>(Xb, wq, bq, wk, bk, wv, bv, Qraw, Kraw, Vt);
  }

  rope_kernel<<<(S_LEN * 2048) / 256, 256, 0, stream>>>(Qraw, Kraw, pos);
  attn2_kernel<<<dim3(64, NH), 64, 0, stream>>>(Qraw, Kraw, Vt, Ctx);

  if (fast) {
    gemm_out_fast<<<dim3(16, 28), 256, 0, stream>>>(Ctx, Wob, out);
  } else {
    gemm_out_slow<<<dim3(16, 28), 256, 0, stream>>>(Ctx, wo, out);
  }
}

// Round 3
// 614.380 us; speedup vs baseline: 1.2262x; 1.0985x over previous
//
#include <hip/hip_runtime.h>
#include <hip/hip_bf16.h>
#include <cmath>

#define H_DIM 3584
#define NH 28
#define NKV 4
#define HD 128
#define S_LEN 2048
#define KQ 3584
#define KV_DIM 512
#define LDSK 72   // padded k-stride for fallback gemm

typedef __attribute__((ext_vector_type(8))) short bf16x8;
typedef __attribute__((ext_vector_type(4))) float f32x4;

__device__ __forceinline__ unsigned short f2bf(float f) {
  unsigned int u = __builtin_bit_cast(unsigned int, f);
  u += 0x7fffu + ((u >> 16) & 1u);
  return (unsigned short)(u >> 16);
}
__device__ __forceinline__ float bf2f(unsigned short h) {
  unsigned int u = ((unsigned int)h) << 16;
  return __builtin_bit_cast(float, u);
}

// ---------------- elementwise: fp32 -> bf16 ----------------
__global__ void cvt_f32_bf16(const float* __restrict__ in,
                             unsigned short* __restrict__ out, int n4) {
  int i = blockIdx.x * blockDim.x + threadIdx.x;
  if (i >= n4) return;
  float4 f = ((const float4*)in)[i];
  ushort4 v = make_ushort4(f2bf(f.x), f2bf(f.y), f2bf(f.z), f2bf(f.w));
  ((ushort4*)out)[i] = v;
}

// ---------------- RoPE on Q and K (in-place, bf16) ----------------
__global__ void rope_kernel(unsigned short* __restrict__ Q,
                            unsigned short* __restrict__ Kr,
                            const int* __restrict__ pos_ids) {
  int gid = blockIdx.x * blockDim.x + threadIdx.x; // 2048 * 2048
  int s = gid >> 11;
  int p = gid & 2047;
  float pos = (float)pos_ids[s];
  unsigned short* ptr;
  int i;
  if (p < 1792) {           // Q: 28 heads * 64 pairs
    int head = p >> 6; i = p & 63;
    ptr = Q + (size_t)s * H_DIM + head * HD + i;
  } else {                  // K: 4 heads * 64 pairs
    int pk = p - 1792; int head = pk >> 6; i = pk & 63;
    ptr = Kr + (size_t)s * KV_DIM + head * HD + i;
  }
  float invf = exp2f(-(float)i * (19.931568569324174f / 64.0f)); // theta^(-i/64)
  float fr = pos * invf;
  float sn, cs;
  sincosf(fr, &sn, &cs);
  float x0 = bf2f(ptr[0]), x1 = bf2f(ptr[64]);
  ptr[0]  = f2bf(x0 * cs - x1 * sn);
  ptr[64] = f2bf(x1 * cs + x0 * sn);
}

// =======================================================================
// FAST GEMM v2: 128x128 tile, BK=64, global_load_lds width 16,
// explicit 2-phase LDS double-buffer (stage t+1 issued before compute t,
// one barrier per K-step), distinct LDS symbols for alias disambiguation.
// =======================================================================
__device__ __forceinline__ void gemm_core_db(const unsigned short* __restrict__ A,
                                             const unsigned short* __restrict__ B,
                                             int bm0, f32x4 (&acc)[4][4],
                                             unsigned short* As0, unsigned short* Bs0,
                                             unsigned short* As1, unsigned short* Bs1) {
  const int tid = threadIdx.x, lane = tid & 63, w = tid >> 6;
  const int wr = w >> 1, wc = w & 1, lr = lane & 15, lg = lane >> 4;
  const f32x4 zero4 = {0.f, 0.f, 0.f, 0.f};
#pragma unroll
  for (int m = 0; m < 4; ++m)
#pragma unroll
    for (int n = 0; n < 4; ++n) acc[m][n] = zero4;

  const int lrow = lane >> 3;        // 0..7
  const int lcol = (lane & 7) * 8;   // elem col within 64

  auto stage = [&](unsigned short* as, unsigned short* bs, int k0) {
#pragma unroll
    for (int j = 0; j < 4; ++j) {
      int id = w * 4 + j;            // 0..15, wave-uniform
      int row = id * 8 + lrow;       // 0..127
      __builtin_amdgcn_global_load_lds(
          (const __attribute__((address_space(1))) unsigned int*)(A + (size_t)(bm0 + row) * KQ + k0 + lcol),
          (__attribute__((address_space(3))) unsigned int*)(as + id * 512),
          16, 0, 0);
      __builtin_amdgcn_global_load_lds(
          (const __attribute__((address_space(1))) unsigned int*)(B + (size_t)row * KQ + k0 + lcol),
          (__attribute__((address_space(3))) unsigned int*)(bs + id * 512),
          16, 0, 0);
    }
  };
  auto compute = [&](const unsigned short* as, const unsigned short* bs) {
#pragma unroll
    for (int kh = 0; kh < 2; ++kh) {
      bf16x8 af[4], bfr[4];
#pragma unroll
      for (int m = 0; m < 4; ++m)
        af[m] = *(const bf16x8*)&as[(wr * 64 + m * 16 + lr) * 64 + kh * 32 + lg * 8];
#pragma unroll
      for (int n = 0; n < 4; ++n)
        bfr[n] = *(const bf16x8*)&bs[(wc * 64 + n * 16 + lr) * 64 + kh * 32 + lg * 8];
#pragma unroll
      for (int m = 0; m < 4; ++m)
#pragma unroll
        for (int n = 0; n < 4; ++n)
          acc[m][n] = __builtin_amdgcn_mfma_f32_16x16x32_bf16(af[m], bfr[n], acc[m][n], 0, 0, 0);
    }
  };

  stage(As0, Bs0, 0);
  __syncthreads();
  // KQ/64 = 56 steps (even) -> unrolled by 2 with compile-time buffers
  for (int k0 = 0; k0 < KQ; k0 += 128) {
    stage(As1, Bs1, k0 + 64);        // k0+64 <= 3520 < KQ always
    compute(As0, Bs0);
    __syncthreads();
    if (k0 + 128 < KQ) stage(As0, Bs0, k0 + 128);
    compute(As1, Bs1);
    __syncthreads();
  }
}

__global__ __launch_bounds__(256) void gemm_qkv_fast(
    const unsigned short* __restrict__ Xb,
    const unsigned short* __restrict__ Wqb, const float* __restrict__ bq,
    const unsigned short* __restrict__ Wkb, const float* __restrict__ bk,
    const unsigned short* __restrict__ Wvb, const float* __restrict__ bv,
    unsigned short* __restrict__ Qraw, unsigned short* __restrict__ Kraw,
    unsigned short* __restrict__ Vt) {
  __shared__ unsigned short As0[8192], Bs0[8192], As1[8192], Bs1[8192];
  // XCD swizzle: 576 blocks, 72 per XCD
  const int id = blockIdx.x;
  const int swz = (id & 7) * 72 + (id >> 3);
  const int bm0 = (swz & 15) * 128;
  const int cb = swz >> 4;  // 0..35
  const unsigned short* Brows; const float* bias; int seg, c0;
  if (cb < 28)      { seg = 0; c0 = cb * 128;        Brows = Wqb + (size_t)c0 * KQ; bias = bq + c0; }
  else if (cb < 32) { seg = 1; c0 = (cb - 28) * 128; Brows = Wkb + (size_t)c0 * KQ; bias = bk + c0; }
  else              { seg = 2; c0 = (cb - 32) * 128; Brows = Wvb + (size_t)c0 * KQ; bias = bv + c0; }
  f32x4 acc[4][4];
  gemm_core_db(Xb, Brows, bm0, acc, As0, Bs0, As1, Bs1);
  const int tid = threadIdx.x, lane = tid & 63, w = tid >> 6;
  const int wr = w >> 1, wc = w & 1, lr = lane & 15, lg = lane >> 4;
#pragma unroll
  for (int m = 0; m < 4; ++m) {
#pragma unroll
    for (int n = 0; n < 4; ++n) {
      int coll = wc * 64 + n * 16 + lr;
      float bb = bias[coll];
#pragma unroll
      for (int r = 0; r < 4; ++r) {
        int row = bm0 + wr * 64 + m * 16 + lg * 4 + r;
        float v = acc[m][n][r] + bb;
        if (seg == 0)      Qraw[(size_t)row * H_DIM + c0 + coll] = f2bf(v);
        else if (seg == 1) Kraw[(size_t)row * KV_DIM + c0 + coll] = f2bf(v);
        else               Vt[(size_t)(c0 + coll) * S_LEN + row] = f2bf(v);
      }
    }
  }
}

__global__ __launch_bounds__(256) void gemm_out_fast(
    const unsigned short* __restrict__ Ctx,
    const unsigned short* __restrict__ Wob,
    float* __restrict__ out) {
  __shared__ unsigned short As0[8192], Bs0[8192], As1[8192], Bs1[8192];
  // XCD swizzle: 448 blocks, 56 per XCD
  const int id = blockIdx.x;
  const int swz = (id & 7) * 56 + (id >> 3);
  const int bm0 = (swz & 15) * 128;
  const int c0 = (swz >> 4) * 128;
  f32x4 acc[4][4];
  gemm_core_db(Ctx, Wob + (size_t)c0 * KQ, bm0, acc, As0, Bs0, As1, Bs1);
  const int tid = threadIdx.x, lane = tid & 63, w = tid >> 6;
  const int wr = w >> 1, wc = w & 1, lr = lane & 15, lg = lane >> 4;
#pragma unroll
  for (int m = 0; m < 4; ++m)
#pragma unroll
    for (int n = 0; n < 4; ++n) {
      int coll = wc * 64 + n * 16 + lr;
#pragma unroll
      for (int r = 0; r < 4; ++r) {
        int row = bm0 + wr * 64 + m * 16 + lg * 4 + r;
        out[(size_t)row * H_DIM + c0 + coll] = acc[m][n][r];
      }
    }
}

// =======================================================================
// FALLBACK GEMM (inline fp32->bf16 B conversion) — used if ws too small
// =======================================================================
__device__ __forceinline__ void gemm_core_slow(const unsigned short* __restrict__ A,
                                               const float* __restrict__ Brows,
                                               int bm0, f32x4 (&acc)[4][4],
                                               unsigned short* As, unsigned short* Bs) {
  const int tid = threadIdx.x;
  const int lane = tid & 63;
  const int w = tid >> 6;
  const int wr = w >> 1, wc = w & 1;
  const int lr = lane & 15, lg = lane >> 4;
  const f32x4 zero4 = {0.f, 0.f, 0.f, 0.f};
#pragma unroll
  for (int m = 0; m < 4; ++m)
#pragma unroll
    for (int n = 0; n < 4; ++n) acc[m][n] = zero4;

  for (int k0 = 0; k0 < KQ; k0 += 64) {
#pragma unroll
    for (int it = 0; it < 4; ++it) {
      int idx = tid + it * 256;
      int row = idx >> 3;
      int kc = (idx & 7) * 8;
      *(bf16x8*)&As[row * LDSK + kc] =
          *(const bf16x8*)&A[(size_t)(bm0 + row) * KQ + k0 + kc];
    }
#pragma unroll
    for (int it = 0; it < 4; ++it) {
      int idx = tid + it * 256;
      int row = idx >> 3;
      int kc = (idx & 7) * 8;
      const float* src = Brows + (size_t)row * KQ + k0 + kc;
      float4 f0 = *(const float4*)src;
      float4 f1 = *(const float4*)(src + 4);
      bf16x8 b;
      b[0] = (short)f2bf(f0.x); b[1] = (short)f2bf(f0.y);
      b[2] = (short)f2bf(f0.z); b[3] = (short)f2bf(f0.w);
      b[4] = (short)f2bf(f1.x); b[5] = (short)f2bf(f1.y);
      b[6] = (short)f2bf(f1.z); b[7] = (short)f2bf(f1.w);
      *(bf16x8*)&Bs[row * LDSK + kc] = b;
    }
    __syncthreads();
#pragma unroll
    for (int kh = 0; kh < 2; ++kh) {
      bf16x8 af[4], bfr[4];
#pragma unroll
      for (int m = 0; m < 4; ++m)
        af[m] = *(const bf16x8*)&As[(wr * 64 + m * 16 + lr) * LDSK + kh * 32 + lg * 8];
#pragma unroll
      for (int n = 0; n < 4; ++n)
        bfr[n] = *(const bf16x8*)&Bs[(wc * 64 + n * 16 + lr) * LDSK + kh * 32 + lg * 8];
#pragma unroll
      for (int m = 0; m < 4; ++m)
#pragma unroll
        for (int n = 0; n < 4; ++n)
          acc[m][n] = __builtin_amdgcn_mfma_f32_16x16x32_bf16(af[m], bfr[n], acc[m][n], 0, 0, 0);
    }
    __syncthreads();
  }
}

__global__ __launch_bounds__(256) void gemm_qkv_slow(
    const unsigned short* __restrict__ Xb,
    const float* __restrict__ wq, const float* __restrict__ bq,
    const float* __restrict__ wk, const float* __restrict__ bk,
    const float* __restrict__ wv, const float* __restrict__ bv,
    unsigned short* __restrict__ Qraw, unsigned short* __restrict__ Kraw,
    unsigned short* __restrict__ Vt) {
  __shared__ unsigned short As[128 * LDSK];
  __shared__ unsigned short Bs[128 * LDSK];
  const int bm0 = blockIdx.x * 128;
  const int cb = blockIdx.y;
  const float* Brows; const float* bias; int seg, c0;
  if (cb < 28)      { seg = 0; c0 = cb * 128;        Brows = wq + (size_t)c0 * KQ; bias = bq + c0; }
  else if (cb < 32) { seg = 1; c0 = (cb - 28) * 128; Brows = wk + (size_t)c0 * KQ; bias = bk + c0; }
  else              { seg = 2; c0 = (cb - 32) * 128; Brows = wv + (size_t)c0 * KQ; bias = bv + c0; }
  f32x4 acc[4][4];
  gemm_core_slow(Xb, Brows, bm0, acc, As, Bs);
  const int tid = threadIdx.x, lane = tid & 63, w = tid >> 6;
  const int wr = w >> 1, wc = w & 1, lr = lane & 15, lg = lane >> 4;
#pragma unroll
  for (int m = 0; m < 4; ++m) {
#pragma unroll
    for (int n = 0; n < 4; ++n) {
      int coll = wc * 64 + n * 16 + lr;
      float bb = bias[coll];
#pragma unroll
      for (int r = 0; r < 4; ++r) {
        int row = bm0 + wr * 64 + m * 16 + lg * 4 + r;
        float v = acc[m][n][r] + bb;
        if (seg == 0)      Qraw[(size_t)row * H_DIM + c0 + coll] = f2bf(v);
        else if (seg == 1) Kraw[(size_t)row * KV_DIM + c0 + coll] = f2bf(v);
        else               Vt[(size_t)(c0 + coll) * S_LEN + row] = f2bf(v);
      }
    }
  }
}

__global__ __launch_bounds__(256) void gemm_out_slow(
    const unsigned short* __restrict__ Ctx,
    const float* __restrict__ wo,
    float* __restrict__ out) {
  __shared__ unsigned short As[128 * LDSK];
  __shared__ unsigned short Bs[128 * LDSK];
  const int bm0 = blockIdx.x * 128;
  const int c0 = blockIdx.y * 128;
  f32x4 acc[4][4];
  gemm_core_slow(Ctx, wo + (size_t)c0 * KQ, bm0, acc, As, Bs);
  const int tid = threadIdx.x, lane = tid & 63, w = tid >> 6;
  const int wr = w >> 1, wc = w & 1, lr = lane & 15, lg = lane >> 4;
#pragma unroll
  for (int m = 0; m < 4; ++m)
#pragma unroll
    for (int n = 0; n < 4; ++n) {
      int coll = wc * 64 + n * 16 + lr;
#pragma unroll
      for (int r = 0; r < 4; ++r) {
        int row = bm0 + wr * 64 + m * 16 + lg * 4 + r;
        out[(size_t)row * H_DIM + c0 + coll] = acc[m][n][r];
      }
    }
}

// =======================================================================
// Flash attention v3: 1 wave/block, 16 q-rows/wave, 32-key tiles,
// register-double-buffered K prefetch + early V issue, heavy-first
// XCD/KV-group swizzle, setprio around MFMA clusters.
// =======================================================================
__global__ __launch_bounds__(64) void attn3_kernel(
    const unsigned short* __restrict__ Q,
    const unsigned short* __restrict__ K,
    const unsigned short* __restrict__ Vt,
    unsigned short* __restrict__ Ctx) {
  __shared__ unsigned short plds[16][40];
  // bid -> (head, qt): XCD pair {2k,2k+1} owns kv-group k (1MB KV, L2-fits),
  // qt descends (heavy blocks dispatch first across all heads).
  const int bid = blockIdx.x;
  const int xcd = bid & 7;
  const int kvg = xcd >> 1;
  const int m = ((bid >> 3) << 1) | (xcd & 1);  // 0..895 within pair
  const int hsub = m % 7;
  const int qt = 127 - m / 7;
  const int h = kvg * 7 + hsub;
  const int hkv = kvg;
  const int lane = threadIdx.x & 63;
  const int lr = lane & 15, lg = lane >> 4;
  const int q0 = qt * 16;
  const float scale = 0.08838834764831845f;   // 1/sqrt(128)
  const float l2e = 1.4426950408889634f;
  const f32x4 zero4 = {0.f, 0.f, 0.f, 0.f};

  bf16x8 aq[4];
  const unsigned short* qrow = Q + (size_t)(q0 + lr) * H_DIM + h * HD;
#pragma unroll
  for (int ds = 0; ds < 4; ++ds) aq[ds] = *(const bf16x8*)(qrow + ds * 32 + lg * 8);

  f32x4 acc[8];
#pragma unroll
  for (int t = 0; t < 8; ++t) acc[t] = zero4;
  float mrun[4] = {-1e30f, -1e30f, -1e30f, -1e30f};
  float lrun[4] = {0.f, 0.f, 0.f, 0.f};

  const unsigned short* kbase = K + hkv * HD + (size_t)lr * KV_DIM + lg * 8;
  const unsigned short* vbase = Vt + (size_t)(hkv * HD + lr) * S_LEN + lg * 8;

  const int nkt = (q0 + 47) >> 5;   // 32-key tiles, causal

  bf16x8 kra[2][4], krb[2][4];      // two K-tile register buffers

  auto loadk = [&](bf16x8 (&dst)[2][4], int kt) {
    const int kk0 = kt * 32;
#pragma unroll
    for (int kf = 0; kf < 2; ++kf)
#pragma unroll
      for (int ds = 0; ds < 4; ++ds)
        dst[kf][ds] = *(const bf16x8*)(kbase + (size_t)(kk0 + kf * 16) * KV_DIM + ds * 32);
  };

  auto process = [&](int kt, bf16x8 (&cur)[2][4], bf16x8 (&nxt)[2][4]) {
    const int kk0 = kt * 32;
    if (kt + 1 < nkt) loadk(nxt, kt + 1);   // prefetch next K tile
    bf16x8 vreg[8];                          // early V issue
#pragma unroll
    for (int t = 0; t < 8; ++t)
      vreg[t] = *(const bf16x8*)(vbase + (size_t)(t * 16) * S_LEN + kk0);
    f32x4 s[2];
    s[0] = zero4; s[1] = zero4;
    __builtin_amdgcn_s_setprio(1);
#pragma unroll
    for (int ds = 0; ds < 4; ++ds) {
      s[0] = __builtin_amdgcn_mfma_f32_16x16x32_bf16(aq[ds], cur[0][ds], s[0], 0, 0, 0);
      s[1] = __builtin_amdgcn_mfma_f32_16x16x32_bf16(aq[ds], cur[1][ds], s[1], 0, 0, 0);
    }
    __builtin_amdgcn_s_setprio(0);
    float sv[2][4];
#pragma unroll
    for (int kf = 0; kf < 2; ++kf) {
      int key = kk0 + kf * 16 + lr;
#pragma unroll
      for (int r = 0; r < 4; ++r) {
        int qr = q0 + lg * 4 + r;
        sv[kf][r] = (key > qr) ? -1e30f : s[kf][r] * scale;
      }
    }
    float mt[4];
#pragma unroll
    for (int r = 0; r < 4; ++r) mt[r] = fmaxf(sv[0][r], sv[1][r]);
#pragma unroll
    for (int sh = 0; sh < 4; ++sh) {
      int off = 1 << sh;
#pragma unroll
      for (int r = 0; r < 4; ++r) mt[r] = fmaxf(mt[r], __shfl_xor(mt[r], off));
    }
    bool need = false;
#pragma unroll
    for (int r = 0; r < 4; ++r) need = need || (mt[r] > mrun[r]);
    if (__any(need)) {
#pragma unroll
      for (int r = 0; r < 4; ++r) {
        float mnew = fmaxf(mrun[r], mt[r]);
        float alpha = exp2f((mrun[r] - mnew) * l2e);
        mrun[r] = mnew;
        lrun[r] *= alpha;
#pragma unroll
        for (int t = 0; t < 8; ++t) acc[t][r] *= alpha;
      }
    }
    float ml2[4];
#pragma unroll
    for (int r = 0; r < 4; ++r) ml2[r] = mrun[r] * l2e;
    float lt[4] = {0.f, 0.f, 0.f, 0.f};
#pragma unroll
    for (int kf = 0; kf < 2; ++kf)
#pragma unroll
      for (int r = 0; r < 4; ++r) {
        float p = exp2f(sv[kf][r] * l2e - ml2[r]);
        lt[r] += p;
        plds[lg * 4 + r][kf * 16 + lr] = f2bf(p);
      }
#pragma unroll
    for (int sh = 0; sh < 4; ++sh) {
      int off = 1 << sh;
#pragma unroll
      for (int r = 0; r < 4; ++r) lt[r] += __shfl_xor(lt[r], off);
    }
#pragma unroll
    for (int r = 0; r < 4; ++r) lrun[r] += lt[r];
    bf16x8 pa = *(const bf16x8*)&plds[lr][lg * 8];
    __builtin_amdgcn_s_setprio(1);
#pragma unroll
    for (int t = 0; t < 8; ++t)
      acc[t] = __builtin_amdgcn_mfma_f32_16x16x32_bf16(pa, vreg[t], acc[t], 0, 0, 0);
    __builtin_amdgcn_s_setprio(0);
  };

  loadk(kra, 0);
  for (int kt = 0; kt < nkt; kt += 2) {
    process(kt, kra, krb);
    if (kt + 1 < nkt) process(kt + 1, krb, kra);
  }

#pragma unroll
  for (int r = 0; r < 4; ++r) {
    float inv = 1.0f / lrun[r];
#pragma unroll
    for (int t = 0; t < 8; ++t)
      Ctx[(size_t)(q0 + lg * 4 + r) * H_DIM + h * HD + t * 16 + lr] = f2bf(acc[t][r] * inv);
  }
}

extern "C" void kernel_launch(void* const* d_in, const int* in_sizes, int n_in,
                              void* d_out, int out_size, void* d_ws, size_t ws_size,
                              hipStream_t stream) {
  (void)in_sizes; (void)n_in; (void)out_size;
  const float* hidden = (const float*)d_in[0];
  const float* wq = (const float*)d_in[1];
  const float* bq = (const float*)d_in[2];
  const float* wk = (const float*)d_in[3];
  const float* bk = (const float*)d_in[4];
  const float* wv = (const float*)d_in[5];
  const float* bv = (const float*)d_in[6];
  const float* wo = (const float*)d_in[7];
  const int* pos = (const int*)d_in[8];
  float* out = (float*)d_out;

  const size_t N_X   = (size_t)S_LEN * H_DIM;   // 7,340,032
  const size_t N_KV  = (size_t)S_LEN * KV_DIM;  // 1,048,576
  const size_t N_WQ  = (size_t)NH * HD * H_DIM; // 12,845,056
  const size_t N_WK  = (size_t)NKV * HD * H_DIM;// 1,835,008

  unsigned short* Xb   = (unsigned short*)d_ws;
  unsigned short* Qraw = Xb   + N_X;
  unsigned short* Kraw = Qraw + N_X;
  unsigned short* Vt   = Kraw + N_KV;
  unsigned short* Ctx  = Vt   + N_KV;
  unsigned short* Wqb  = Ctx  + N_X;
  unsigned short* Wkb  = Wqb  + N_WQ;
  unsigned short* Wvb  = Wkb  + N_WK;
  unsigned short* Wob  = Wvb  + N_WK;

  const size_t NEED_FAST = (3 * N_X + 2 * N_KV + 2 * N_WQ + 2 * N_WK) * sizeof(unsigned short);
  const bool fast = ws_size >= NEED_FAST;

  cvt_f32_bf16<<<(int)(N_X / 4 / 256), 256, 0, stream>>>(hidden, Xb, (int)(N_X / 4));

  if (fast) {
    cvt_f32_bf16<<<(int)(N_WQ / 4 / 256), 256, 0, stream>>>(wq, Wqb, (int)(N_WQ / 4));
    cvt_f32_bf16<<<(int)(N_WK / 4 / 256), 256, 0, stream>>>(wk, Wkb, (int)(N_WK / 4));
    cvt_f32_bf16<<<(int)(N_WK / 4 / 256), 256, 0, stream>>>(wv, Wvb, (int)(N_WK / 4));
    cvt_f32_bf16<<<(int)(N_WQ / 4 / 256), 256, 0, stream>>>(wo, Wob, (int)(N_WQ / 4));
    gemm_qkv_fast<<<576, 256, 0, stream>>>(Xb, Wqb, bq, Wkb, bk, Wvb, bv, Qraw, Kraw, Vt);
  } else {
    gemm_qkv_slow<<<dim3(16, 36), 256, 0, stream>>>(Xb, wq, bq, wk, bk, wv, bv, Qraw, Kraw, Vt);
  }

  rope_kernel<<<(S_LEN * 2048) / 256, 256, 0, stream>>>(Qraw, Kraw, pos);
  attn3_kernel<<<NH * 128, 64, 0, stream>>>(Qraw, Kraw, Vt, Ctx);

  if (fast) {
    gemm_out_fast<<<448, 256, 0, stream>>>(Ctx, Wob, out);
  } else {
    gemm_out_slow<<<dim3(16, 28), 256, 0, stream>>>(Ctx, wo, out);
  }
}